// Round 3
// baseline (188.665 us; speedup 1.0000x reference)
//
#include <hip/hip_runtime.h>

// 3x3 conv (sparse weights treated dense), NCHW/OIHW, stride1 pad1, fp32 I/O.
// B=32, CIN=COUT=256, H=W=56.
//
// R3: implicit-GEMM, mfma_f32_16x16x32_bf16.
//  - prep_xp: coalesced LDS-transpose -> xp bf16 channels-last padded [b][58][58][256]
//  - prep_wb: w OIHW fp32 -> wb bf16 [cout][tap][cin]
//  - conv_mfma: block = 128 couts x 112 pixels (2 output rows), 4 waves.
//    Weights: A-fragments loaded DIRECTLY global->VGPR (L2-resident, 16B/lane),
//    pipelined one tap ahead. No weight LDS, no per-tap barriers.
//    x: staged per 32-cin block into LDS, T14 split (load regs early, ds_write
//    after barrier). 2 barriers per cin-block (16 total vs R2's 144+16).

typedef __attribute__((ext_vector_type(8))) short short8;
typedef __attribute__((ext_vector_type(4))) float f32x4;
typedef __attribute__((ext_vector_type(4))) int i32x4;

constexpr int BB = 32, CIN = 256, COUT = 256, H = 56, W = 56, HW = H * W;
constexpr int HP = 58, WP = 58;
constexpr int XSTR = 40;                 // LDS cin stride (32 padded to 40 elems = 80B)

constexpr size_t XP_ELEMS = (size_t)BB * HP * WP * CIN;
constexpr size_t WB_ELEMS = (size_t)COUT * 9 * CIN;
constexpr size_t WS_NEEDED = (XP_ELEMS + WB_ELEMS) * 2;

__device__ __forceinline__ ushort f2bf(float f) {
    unsigned x = __float_as_uint(f);
    unsigned r = (x + 0x7FFFu + ((x >> 16) & 1u)) >> 16;   // RNE
    return (ushort)r;
}

// ---------------- prep kernels ----------------

__global__ __launch_bounds__(256)
void prep_xp(const float* __restrict__ x, ushort* __restrict__ xp) {
    const int bi = blockIdx.x;            // b*58 + padded row i
    const int b = bi / HP, i = bi % HP;
    ushort* dst = xp + (size_t)bi * WP * CIN;
    const int tid = threadIdx.x;

    if (i == 0 || i == HP - 1) {
        i32x4 z = {0, 0, 0, 0};
        for (int k = tid; k < WP * CIN / 8; k += 256) ((i32x4*)dst)[k] = z;
        return;
    }

    __shared__ ushort t[W][CIN + 2];      // +2 pad: LDS write stride 516B
    const int lane = tid & 63, wv = tid >> 6;
    if (lane < W) {
        const float* src = x + (size_t)b * CIN * HW + (size_t)(i - 1) * W + lane;
        for (int cin = wv; cin < CIN; cin += 4)
            t[lane][cin] = f2bf(src[(size_t)cin * HW]);
    }
    __syncthreads();
    for (int c = 0; c < WP; ++c)
        dst[c * CIN + tid] = (c == 0 || c == WP - 1) ? (ushort)0 : t[c - 1][tid];
}

__global__ __launch_bounds__(256)
void prep_wb(const float* __restrict__ w, ushort* __restrict__ wb) {
    const int d = blockIdx.x * 256 + threadIdx.x;  // (cout*9+tap)*256+cin
    const int cin = d & 255;
    const int rest = d >> 8;
    const int tap = rest % 9;
    const int cout = rest / 9;
    wb[d] = f2bf(w[((size_t)cout * CIN + cin) * 9 + tap]);
}

// ---------------- MFMA conv ----------------

__global__ __launch_bounds__(256, 2)
void conv_mfma(const ushort* __restrict__ xp, const ushort* __restrict__ wb,
               float* __restrict__ out) {
    // XCD-aware swizzle: 1792 blocks = 8 * 224
    int bx = blockIdx.x;
    bx = (bx & 7) * 224 + (bx >> 3);

    const int mt = bx & 1;                 // 2 cout tiles of 128
    const int nt = bx >> 1;                // 896 = 32 b * 28 row-pairs
    const int b  = nt / 28;
    const int h0 = (nt % 28) * 2;

    const int tid  = threadIdx.x;
    const int wv   = tid >> 6;             // wave -> couts [32wv, 32wv+32)
    const int lane = tid & 63;
    const int ml   = lane & 15;
    const int g    = lane >> 4;

    __shared__ ushort xs[4 * WP * XSTR];   // 18560B

    // A-fragment global bases: lane holds W[cout][k=8g..8g+7] for tap/cb offsets
    const ushort* wb0 = wb + (size_t)(mt * 128 + wv * 32 + ml) * 9 * CIN + 8 * g;
    const ushort* wb1 = wb0 + (size_t)16 * 9 * CIN;

    // B-fragment LDS offsets: lane holds X[k=8g..][pix=nf*16+ml]
    int boff[7];
    #pragma unroll
    for (int nf = 0; nf < 7; ++nf) {
        const int p = nf * 16 + ml;
        const int hl = (p >= 56) ? 1 : 0;
        const int wl = p - 56 * hl;
        boff[nf] = (hl * WP + wl) * XSTR + 8 * g;
    }

    // staging role: 232 threads, one (row r, col c) each, 64B per cin-block
    const int sr = tid / WP, sc = tid % WP;
    const bool do_stage = (tid < 4 * WP);
    const ushort* sp = xp + ((size_t)(b * HP + h0) * WP + sr * WP + sc) * CIN;
    ushort* sd = &xs[(sr * WP + sc) * XSTR];

    f32x4 acc[2][7] = {};
    i32x4 stg[4];

    if (do_stage) {
        const i32x4* s = (const i32x4*)sp;
        stg[0] = s[0]; stg[1] = s[1]; stg[2] = s[2]; stg[3] = s[3];
    }

    for (int cb = 0; cb < 8; ++cb) {
        __syncthreads();                   // xs free to overwrite
        if (do_stage) {
            *(i32x4*)(sd)      = stg[0];
            *(i32x4*)(sd + 8)  = stg[1];
            *(i32x4*)(sd + 16) = stg[2];
            *(i32x4*)(sd + 24) = stg[3];
        }
        if (cb < 7 && do_stage) {          // issue next block's loads early
            const i32x4* s = (const i32x4*)(sp + (cb + 1) * 32);
            stg[0] = s[0]; stg[1] = s[1]; stg[2] = s[2]; stg[3] = s[3];
        }
        __syncthreads();                   // xs ready

        const ushort* wa0 = wb0 + cb * 32;
        const ushort* wa1 = wb1 + cb * 32;
        short8 a0 = *(const short8*)wa0;
        short8 a1 = *(const short8*)wa1;
        #pragma unroll
        for (int tap = 0; tap < 9; ++tap) {
            short8 n0, n1;
            if (tap < 8) {                 // prefetch next tap's A-frags (L2)
                n0 = *(const short8*)(wa0 + (tap + 1) * CIN);
                n1 = *(const short8*)(wa1 + (tap + 1) * CIN);
            }
            const int kh = tap / 3, kw = tap - kh * 3;
            const int toff = (kh * WP + kw) * XSTR;
            #pragma unroll
            for (int nf = 0; nf < 7; ++nf) {
                const short8 bf = *(const short8*)&xs[boff[nf] + toff];
                acc[0][nf] = __builtin_amdgcn_mfma_f32_16x16x32_bf16(a0, bf, acc[0][nf], 0, 0, 0);
                acc[1][nf] = __builtin_amdgcn_mfma_f32_16x16x32_bf16(a1, bf, acc[1][nf], 0, 0, 0);
            }
            if (tap < 8) { a0 = n0; a1 = n1; }
        }
    }

    // epilogue: D[row=4g+r][col=ml] per m89 (verified by R2 pass)
    float* ob = out + ((size_t)b * COUT + mt * 128 + wv * 32) * HW;
    #pragma unroll
    for (int fm = 0; fm < 2; ++fm)
        #pragma unroll
        for (int nf = 0; nf < 7; ++nf)
            #pragma unroll
            for (int r = 0; r < 4; ++r) {
                const int cout_l = fm * 16 + 4 * g + r;
                const int p = nf * 16 + ml;
                const int hh = (p >= 56) ? 1 : 0;
                const int ww = p - 56 * hh;
                ob[(size_t)cout_l * HW + (h0 + hh) * W + ww] = acc[fm][nf][r];
            }
}

// ---------------- R1 fallback (fp32 sparse direct) ----------------

constexpr int WSZ = CIN * 9;
constexpr int NIN = 54 * 54;

__global__ __launch_bounds__(256)
void sparse_conv3x3(const float* __restrict__ x,
                    const float* __restrict__ wgt,
                    float* __restrict__ out) {
    const int bc = blockIdx.x, cout = bc % COUT, b = bc / COUT;
    const int tid = threadIdx.x;
    __shared__ int2 s_ent[WSZ];
    __shared__ unsigned char s_kk[WSZ];
    __shared__ int s_cnt[257];
    const float* wc = wgt + (size_t)cout * WSZ;
    float mv[9]; int cnt = 0;
    #pragma unroll
    for (int i = 0; i < 9; ++i) { mv[i] = wc[tid * 9 + i]; if (mv[i] != 0.0f) cnt++; }
    s_cnt[tid] = cnt; __syncthreads();
    if (tid == 0) { int run = 0; for (int t = 0; t < 256; ++t) { int c = s_cnt[t]; s_cnt[t] = run; run += c; } s_cnt[256] = run; }
    __syncthreads();
    { int pos = s_cnt[tid];
      #pragma unroll
      for (int i = 0; i < 9; ++i) if (mv[i] != 0.0f) {
          const int kh = i / 3, kw = i - kh * 3;
          int2 e; e.x = (tid * HW + (kh - 1) * W + (kw - 1)) * 4; e.y = __float_as_int(mv[i]);
          s_ent[pos] = e; s_kk[pos] = (unsigned char)(kh | (kw << 4)); pos++; } }
    __syncthreads();
    const int nnz = s_cnt[256];
    const char* xb = (const char*)(x + (size_t)b * CIN * HW);
    float* ob = out + (size_t)bc * HW;
    for (int o = tid; o < HW; o += 256) {
        int h, w; bool interior = (o < NIN);
        if (interior) { h = 1 + o / 54; w = 1 + (o - (h - 1) * 54); }
        else { int o2 = o - NIN;
            if (o2 < 56) { h = 0; w = o2; } else if (o2 < 112) { h = 55; w = o2 - 56; }
            else if (o2 < 166) { h = 1 + (o2 - 112); w = 0; } else { h = 1 + (o2 - 166); w = 55; } }
        const char* pb = xb + (size_t)(h * W + w) * 4;
        float acc = 0.0f;
        if (interior) {
            #pragma unroll 4
            for (int e = 0; e < nnz; ++e) { const int2 en = s_ent[e];
                acc = fmaf(__int_as_float(en.y), *(const float*)(pb + en.x), acc); }
        } else {
            const int h1 = h - 1, w1 = w - 1;
            for (int e = 0; e < nnz; ++e) { const int2 en = s_ent[e]; const int kk = s_kk[e];
                const int hh = h1 + (kk & 15), ww = w1 + (kk >> 4);
                if ((unsigned)hh < (unsigned)H && (unsigned)ww < (unsigned)W)
                    acc = fmaf(__int_as_float(en.y), *(const float*)(pb + en.x), acc); } }
        ob[h * W + w] = acc;
    }
}

// ---------------- launch ----------------

extern "C" void kernel_launch(void* const* d_in, const int* in_sizes, int n_in,
                              void* d_out, int out_size, void* d_ws, size_t ws_size,
                              hipStream_t stream) {
    const float* x = (const float*)d_in[0];
    const float* w = (const float*)d_in[1];
    float* out = (float*)d_out;

    if (ws_size >= WS_NEEDED) {
        ushort* xp = (ushort*)d_ws;
        ushort* wbp = xp + XP_ELEMS;
        prep_xp<<<BB * HP, 256, 0, stream>>>(x, xp);
        prep_wb<<<(int)(WB_ELEMS / 256), 256, 0, stream>>>(w, wbp);
        conv_mfma<<<1792, 256, 0, stream>>>(xp, wbp, out);
    } else {
        sparse_conv3x3<<<BB * COUT, 256, 0, stream>>>(x, w, out);
    }
}